// Round 4
// baseline (1411.268 us; speedup 1.0000x reference)
//
#include <hip/hip_runtime.h>
#include <stdint.h>

#define SDR_SIZE   2048
#define CAPACITY   131072
#define TOPK       32
#define CDIM       384

// ws layout (int32 words):
// [192]     candidate count (zeroed via hipMemsetAsync each call)
// [256..]   candidate keys: (overlap << 17) | (131071 - row)

// Dense streaming dot: 1 wave per row, float4 coalesced, query L1-resident.
// Sequential 1.07 GB stream @ ~6 TB/s beats the 40-column gather (~300-500 MB
// of scattered lines @ ~1.5-2 TB/s) because skipped lines inside a DRAM page
// don't save proportional bus time.
__global__ __launch_bounds__(256) void k_overlap(const float* __restrict__ bank,
                                                 const float* __restrict__ q,
                                                 const int* __restrict__ mask,  // bool -> int32
                                                 int* __restrict__ w, int cap) {
    const int wave = (blockIdx.x * 256 + (int)threadIdx.x) >> 6;
    const int lane = threadIdx.x & 63;
    const float4* rp = (const float4*)(bank + (size_t)wave * SDR_SIZE);
    const float4* qp = (const float4*)q;
    float acc = 0.0f;
    #pragma unroll
    for (int i = 0; i < 8; i++) {
        float4 v  = rp[lane + i * 64];   // 1 KiB per wave per iter, coalesced
        float4 qq = qp[lane + i * 64];   // L1 hit after first row on the CU
        acc += v.x * qq.x + v.y * qq.y + v.z * qq.z + v.w * qq.w;
    }
    // wave sum — integer-valued floats, exact in any order
    for (int off = 1; off < 64; off <<= 1) acc += __shfl_xor(acc, off);
    if (lane == 0) {
        int ov = (int)acc;               // exact (<= nact <= ~56)
        // ov >= 12  <=>  (float)ov/40.0f >= 0.3f  (bit-exact vs reference)
        if (mask[wave] != 0 && ov >= 12) {
            int p = atomicAdd(&w[192], 1);
            if (p < cap) w[256 + p] = (ov << 17) | (131071 - wave);
        }
    }
}

__global__ void k_select(const float* __restrict__ content,
                         const int* __restrict__ w,
                         float* __restrict__ out, int cap) {
    __shared__ unsigned int s_top[TOPK];
    int t = threadIdx.x;
    int m = w[192];
    if (m > cap) m = cap;
    int kcount = (m < TOPK) ? m : TOPK;
    if (t < 64) {
        // single-wave repeated strict-max over unique keys
        unsigned int prev = 0xFFFFFFFFu;
        for (int s = 0; s < kcount; s++) {
            unsigned int best = 0;  // valid keys > 0 (overlap >= 12)
            for (int i = t; i < m; i += 64) {
                unsigned int k = (unsigned int)w[256 + i];
                if (k < prev && k > best) best = k;
            }
            for (int off = 1; off < 64; off <<= 1) {
                unsigned int o = (unsigned int)__shfl_xor((int)best, off);
                best = o > best ? o : best;
            }
            prev = best;            // all 64 lanes agree
            if (t == 0) s_top[s] = best;
        }
    }
    __syncthreads();
    // contents: [32, 384]; zero below-threshold / empty slots
    for (int i = t; i < TOPK * CDIM; i += 256) {
        int s = i / CDIM, d = i - s * CDIM;
        float val = 0.0f;
        if (s < kcount) {
            int idx = CAPACITY - 1 - (int)(s_top[s] & 0x1FFFFu);
            val = content[(size_t)idx * CDIM + d];
        }
        out[i] = val;
    }
    // top_sim: [32]
    if (t < TOPK) {
        float sv = 0.0f;
        if (t < kcount) sv = (float)(s_top[t] >> 17) / 40.0f;
        out[TOPK * CDIM + t] = sv;
    }
}

extern "C" void kernel_launch(void* const* d_in, const int* in_sizes, int n_in,
                              void* d_out, int out_size, void* d_ws, size_t ws_size,
                              hipStream_t stream) {
    const float* query   = (const float*)d_in[0];
    const float* bank    = (const float*)d_in[1];
    const float* content = (const float*)d_in[2];
    const int* mask      = (const int*)d_in[3];  // bool -> int32 per harness
    float* out = (float*)d_out;
    int* w = (int*)d_ws;

    size_t words = ws_size / 4;
    int cap = (int)((words > 256) ? (words - 256) : 0);
    if (cap > 65536) cap = 65536;

    // zero the candidate counter (ws is poisoned 0xAA before every call)
    hipMemsetAsync((void*)(w + 192), 0, 4, stream);
    // 1 wave per row, 4 waves/block
    k_overlap<<<CAPACITY / 4, 256, 0, stream>>>(bank, query, mask, w, cap);
    k_select<<<1, 256, 0, stream>>>(content, w, out, cap);
}